// Round 2
// baseline (774.736 us; speedup 1.0000x reference)
//
#include <hip/hip_runtime.h>

typedef unsigned short u16;
typedef unsigned int u32;

#define GN 100000
#define GE 1600000

typedef __bf16 bf16x8 __attribute__((ext_vector_type(8)));
typedef float f32x4 __attribute__((ext_vector_type(4)));

__device__ __forceinline__ float bl(u32 u){ return __uint_as_float(u << 16); }
__device__ __forceinline__ float bh(u32 u){ return __uint_as_float(u & 0xffff0000u); }
__device__ __forceinline__ u16 f2bf(float f){
    u32 u = __float_as_uint(f);
    u32 r = (u + 0x7fffu + ((u >> 16) & 1u)) >> 16;
    return (u16)r;
}

// ---- init: zero deg+colsum; detect edge int32/int64; detect x f32/bf16 ----
// flags[0]: 1 => edge_index stored as int64 (little-endian pairs)
// flags[1]: 1 => float tensors stored as float32, 0 => bf16
__global__ void __launch_bounds__(256) k_init(const int* ei, const u32* xraw,
                                              int* deg, float* colsum, int* flags){
    int i = blockIdx.x * 256 + threadIdx.x;
    if (i < GN) deg[i] = 0;
    int t = threadIdx.x;
    if (blockIdx.x == 0){
        __shared__ int s_any[4];
        colsum[t] = 0.f;
        // sample odd dword positions: int64 => all high dwords are 0
        int v = 0;
        #pragma unroll
        for (int j = 0; j < 4; ++j){
            int k = t * 4 + j;                // k in [0,1024)
            v |= ei[2 * k * 1000 + 1];        // dword pos <= 2046001 < 3.2M
        }
        #pragma unroll
        for (int m = 1; m < 64; m <<= 1) v |= __shfl_xor(v, m);
        if ((t & 63) == 0) s_any[t >> 6] = v;
        __syncthreads();
        if (t == 0){
            int any = s_any[0] | s_any[1] | s_any[2] | s_any[3];
            flags[0] = (any == 0) ? 1 : 0;
        }
    }
    if (blockIdx.x == 1){
        __shared__ int s_cnt[4];
        // low u16 of each dword: for bf16 data it's a bf16 of ~N(0,1)
        // (exponent in [100,140] essentially always); for f32 data it's
        // random mantissa bits (~16% hit rate). Vote over 1024 dwords.
        int cnt = 0;
        #pragma unroll
        for (int j = 0; j < 4; ++j){
            int idx = (t * 4 + j) * 6000 + 3;     // < 6.15M dwords, safe both ways
            u32 u = xraw[idx];
            int e = (u >> 7) & 0xFF;
            cnt += (e >= 100 && e <= 140) ? 1 : 0;
        }
        #pragma unroll
        for (int m = 1; m < 64; m <<= 1) cnt += __shfl_xor(cnt, m);
        if ((t & 63) == 0) s_cnt[t >> 6] = cnt;
        __syncthreads();
        if (t == 0){
            int tot = s_cnt[0] + s_cnt[1] + s_cnt[2] + s_cnt[3];
            flags[1] = (tot > 512) ? 0 : 1;       // many hits => bf16
        }
    }
}

// ---- convert x -> internal bf16 (copy if already bf16) ----
__global__ void __launch_bounds__(256) k_convx(const void* x, const int* flags, u16* xb){
    int gid = blockIdx.x * 256 + threadIdx.x;     // one 8-element chunk
    if (gid >= GN * 16) return;
    if (flags[1]){
        const uint4* xf = (const uint4*)x;
        uint4 a = xf[gid * 2], b = xf[gid * 2 + 1];
        u32 r0 = (u32)f2bf(__uint_as_float(a.x)) | ((u32)f2bf(__uint_as_float(a.y)) << 16);
        u32 r1 = (u32)f2bf(__uint_as_float(a.z)) | ((u32)f2bf(__uint_as_float(a.w)) << 16);
        u32 r2 = (u32)f2bf(__uint_as_float(b.x)) | ((u32)f2bf(__uint_as_float(b.y)) << 16);
        u32 r3 = (u32)f2bf(__uint_as_float(b.z)) | ((u32)f2bf(__uint_as_float(b.w)) << 16);
        uint4 o = {r0, r1, r2, r3};
        ((uint4*)xb)[gid] = o;
    } else {
        ((uint4*)xb)[gid] = ((const uint4*)x)[gid];
    }
}

// ---- convert all params -> contiguous bf16 block ----
// layout: Wl[49152] | Wr[49152] | b[384] | gamma[384] | beta[384]
//         | wlout[128] | wrout[128] | bout[1]   (total 99713)
#define WOFF_WR    49152
#define WOFF_B     98304
#define WOFF_G     98688
#define WOFF_BE    99072
#define WOFF_WLO   99456
#define WOFF_WRO   99584
#define WOFF_BO    99712
#define WTOT       99713
__global__ void __launch_bounds__(256) k_convw(const void* Wl, const void* Wr, const void* b,
                                               const void* g, const void* be, const void* wlo,
                                               const void* wro, const void* bo,
                                               const int* flags, u16* wbuf){
    int i = blockIdx.x * 256 + threadIdx.x;
    if (i >= WTOT) return;
    const void* s; int k;
    if      (i < WOFF_WR ){ s = Wl;  k = i; }
    else if (i < WOFF_B  ){ s = Wr;  k = i - WOFF_WR; }
    else if (i < WOFF_G  ){ s = b;   k = i - WOFF_B; }
    else if (i < WOFF_BE ){ s = g;   k = i - WOFF_G; }
    else if (i < WOFF_WLO){ s = be;  k = i - WOFF_BE; }
    else if (i < WOFF_WRO){ s = wlo; k = i - WOFF_WLO; }
    else if (i < WOFF_BO ){ s = wro; k = i - WOFF_WRO; }
    else                  { s = bo;  k = 0; }
    wbuf[i] = flags[1] ? f2bf(((const float*)s)[k]) : ((const u16*)s)[k];
}

__global__ void __launch_bounds__(256) k_count(const int* ei, const int* flags, int* deg){
    int e = blockIdx.x * 256 + threadIdx.x;
    if (e >= GE) return;
    int d = flags[0] ? ei[2 * (GE + e)] : ei[GE + e];
    atomicAdd(&deg[d], 1);
}

// ---- 3-kernel exclusive scan of deg -> rowptr ----
__global__ void __launch_bounds__(256) k_scan1(const int* deg, int* rowptr, int* bsum){
    __shared__ int ls[256];
    int t = threadIdx.x, b = blockIdx.x;
    int base = b * 1024 + t * 4;
    int d0 = 0, d1 = 0, d2 = 0, d3 = 0;
    if (base + 3 < GN){
        int4 v = *(const int4*)(deg + base);
        d0 = v.x; d1 = v.y; d2 = v.z; d3 = v.w;
    } else {
        if (base     < GN) d0 = deg[base];
        if (base + 1 < GN) d1 = deg[base + 1];
        if (base + 2 < GN) d2 = deg[base + 2];
        if (base + 3 < GN) d3 = deg[base + 3];
    }
    int s = d0 + d1 + d2 + d3;
    ls[t] = s; __syncthreads();
    for (int off = 1; off < 256; off <<= 1){
        int v = (t >= off) ? ls[t - off] : 0;
        __syncthreads();
        ls[t] += v;
        __syncthreads();
    }
    int excl = ls[t] - s;
    if (t == 255) bsum[b] = ls[255];
    if (base     < GN) rowptr[base]     = excl;
    if (base + 1 < GN) rowptr[base + 1] = excl + d0;
    if (base + 2 < GN) rowptr[base + 2] = excl + d0 + d1;
    if (base + 3 < GN) rowptr[base + 3] = excl + d0 + d1 + d2;
}

__global__ void __launch_bounds__(128) k_scan2(const int* bsum, int* boff, int* rowptr){
    __shared__ int ls[128];
    int t = threadIdx.x;
    const int nb = (GN + 1023) / 1024;  // 98
    int v = (t < nb) ? bsum[t] : 0;
    ls[t] = v; __syncthreads();
    for (int off = 1; off < 128; off <<= 1){
        int u = (t >= off) ? ls[t - off] : 0;
        __syncthreads();
        ls[t] += u;
        __syncthreads();
    }
    if (t < nb) boff[t] = ls[t] - v;
    if (t == 0) rowptr[GN] = GE;
}

__global__ void __launch_bounds__(256) k_scan3(int* rowptr, int* cursor, const int* deg,
                                               const int* boff, float* invdeg){
    int i = blockIdx.x * 256 + threadIdx.x;
    if (i >= GN) return;
    int rp = rowptr[i] + boff[i >> 10];
    rowptr[i] = rp;
    cursor[i] = rp;
    int d = deg[i];
    invdeg[i] = (d > 0) ? 1.f / (float)d : 0.f;
}

__global__ void __launch_bounds__(256) k_fill(const int* ei, const int* flags, int* cursor, int* col){
    int e = blockIdx.x * 256 + threadIdx.x;
    if (e >= GE) return;
    int s, d;
    if (flags[0]){ s = ei[2 * e]; d = ei[2 * (GE + e)]; }
    else         { s = ei[e];     d = ei[GE + e]; }
    int pos = atomicAdd(&cursor[d], 1);
    col[pos] = s;
}

// ---- mean aggregation: one wave per node, bf16x2 lanes over 128 features ----
__global__ void __launch_bounds__(256) k_agg(const u16* hin, const int* rowptr, const int* col,
                                             const float* invdeg, u16* amean){
    int wid = threadIdx.x >> 6, lane = threadIdx.x & 63;
    int node = blockIdx.x * 4 + wid;
    if (node >= GN) return;
    int beg = rowptr[node], end = rowptr[node + 1];
    const u32* h32 = (const u32*)hin;
    float lo = 0.f, hi = 0.f;
    int e = beg;
    for (; e + 3 < end; e += 4){
        int c0 = col[e], c1 = col[e+1], c2 = col[e+2], c3 = col[e+3];
        u32 v0 = h32[c0 * 64 + lane];
        u32 v1 = h32[c1 * 64 + lane];
        u32 v2 = h32[c2 * 64 + lane];
        u32 v3 = h32[c3 * 64 + lane];
        lo += bl(v0) + bl(v1) + bl(v2) + bl(v3);
        hi += bh(v0) + bh(v1) + bh(v2) + bh(v3);
    }
    for (; e < end; ++e){
        u32 v = h32[col[e] * 64 + lane];
        lo += bl(v); hi += bh(v);
    }
    float inv = invdeg[node];
    lo *= inv; hi *= inv;
    u32 packed = (u32)f2bf(lo) | ((u32)f2bf(hi) << 16);
    ((u32*)amean)[node * 64 + lane] = packed;
}

// ---- fused GEMM: hout = relu([amean|hin] @ [Wl;Wr] + b), + BN column stats ----
__global__ void __launch_bounds__(256) k_gemm(const u16* amean, const u16* hin,
                                              const u16* Wl, const u16* Wr, const u16* bias,
                                              u16* hout, float* colsum){
    __shared__ __align__(16) u16 wlds[32768];  // [kc=32][c=128][8] bf16, 64KB
    int t = threadIdx.x;
    for (int idx = t; idx < 16384; idx += 256){
        int k = idx >> 7, c = idx & 127;
        wlds[((k >> 3) << 10) + (c << 3) + (k & 7)] = Wl[idx];
        int k2 = k + 128;
        wlds[((k2 >> 3) << 10) + (c << 3) + (k2 & 7)] = Wr[idx];
    }
    __syncthreads();
    int wid = t >> 6, lane = t & 63;
    int quad = lane >> 4, l15 = lane & 15;
    int r0 = blockIdx.x * 128 + wid * 32;
    int rowa = r0 + l15, rowb = rowa + 16;
    f32x4 acc[2][8];
    #pragma unroll
    for (int i = 0; i < 2; i++)
        #pragma unroll
        for (int j = 0; j < 8; j++) acc[i][j] = (f32x4){0.f, 0.f, 0.f, 0.f};

    #pragma unroll
    for (int s = 0; s < 8; ++s){
        const u16* A = (s < 4) ? amean : hin;
        int kk = ((s & 3) << 5) + (quad << 3);
        union { uint4 u; bf16x8 v; } fa0, fa1;
        fa0.u = (rowa < GN) ? *(const uint4*)(A + rowa * 128 + kk) : make_uint4(0,0,0,0);
        fa1.u = (rowb < GN) ? *(const uint4*)(A + rowb * 128 + kk) : make_uint4(0,0,0,0);
        int kc = (s << 2) + quad;
        const u16* wb = &wlds[(kc << 10) + (l15 << 3)];
        #pragma unroll
        for (int cb = 0; cb < 8; ++cb){
            union { uint4 u; bf16x8 v; } fb;
            fb.u = *(const uint4*)(wb + (cb << 7));
            acc[0][cb] = __builtin_amdgcn_mfma_f32_16x16x32_bf16(fa0.v, fb.v, acc[0][cb], 0, 0, 0);
            acc[1][cb] = __builtin_amdgcn_mfma_f32_16x16x32_bf16(fa1.v, fb.v, acc[1][cb], 0, 0, 0);
        }
    }
    __syncthreads();                  // done reading wlds; reuse for stats
    float* sst = (float*)wlds;        // [256]: sum[128], sumsq[128]
    sst[t] = 0.f;
    __syncthreads();

    float bsv[8];
    #pragma unroll
    for (int cb = 0; cb < 8; cb++) bsv[cb] = __uint_as_float(((u32)bias[cb * 16 + l15]) << 16);

    #pragma unroll
    for (int cb = 0; cb < 8; cb++){
        float csum = 0.f, csq = 0.f;
        #pragma unroll
        for (int rb = 0; rb < 2; rb++){
            int rbase = r0 + rb * 16 + quad * 4;
            #pragma unroll
            for (int rr = 0; rr < 4; rr++){
                int row = rbase + rr;
                float v = acc[rb][cb][rr] + bsv[cb];
                v = fmaxf(v, 0.f);
                if (row < GN) hout[row * 128 + cb * 16 + l15] = f2bf(v);
                float vm = (row < GN) ? v : 0.f;
                csum += vm; csq += vm * vm;
            }
        }
        csum += __shfl_xor(csum, 16); csum += __shfl_xor(csum, 32);
        csq  += __shfl_xor(csq, 16);  csq  += __shfl_xor(csq, 32);
        if (quad == 0){
            atomicAdd(&sst[cb * 16 + l15], csum);
            atomicAdd(&sst[128 + cb * 16 + l15], csq);
        }
    }
    __syncthreads();
    atomicAdd(&colsum[t], sst[t]);
}

// ---- BN finalize: per-column scale/shift; re-zero colsum for next layer ----
__global__ void __launch_bounds__(256) k_bn(float* colsum, const u16* gamma, const u16* beta, float* scsh){
    int t = threadIdx.x;
    float s = 0.f, q = 0.f;
    if (t < 128){ s = colsum[t]; q = colsum[128 + t]; }
    __syncthreads();
    colsum[t] = 0.f;
    if (t < 128){
        const float invn = 1.f / (float)GN;
        float mean = s * invn;
        float var = fmaxf(q * invn - mean * mean, 0.f);
        float rstd = rsqrtf(var + 1e-5f);
        float g  = __uint_as_float(((u32)gamma[t]) << 16);
        float be = __uint_as_float(((u32)beta[t]) << 16);
        float sc = g * rstd;
        scsh[t] = sc;
        scsh[128 + t] = be - mean * sc;
    }
}

__global__ void __launch_bounds__(256) k_norm(u16* h, const float* scsh){
    int i = blockIdx.x * 256 + threadIdx.x;    // one 8-elem chunk
    if (i >= GN * 16) return;
    int cg = (i & 15) << 3;
    uint4 u = *((uint4*)h + i);
    u32 in[4] = {u.x, u.y, u.z, u.w};
    u32 res[4];
    #pragma unroll
    for (int j = 0; j < 4; j++){
        float lo = bl(in[j]), hi = bh(in[j]);
        lo = lo * scsh[cg + 2*j]     + scsh[128 + cg + 2*j];
        hi = hi * scsh[cg + 2*j + 1] + scsh[128 + cg + 2*j + 1];
        res[j] = (u32)f2bf(lo) | ((u32)f2bf(hi) << 16);
    }
    uint4 o = {res[0], res[1], res[2], res[3]};
    *((uint4*)h + i) = o;
}

// ---- output head: y = h@Wl_out, r = h@Wr_out (wave per node) ----
__global__ void __launch_bounds__(256) k_dot(const u16* h, const u16* wl, const u16* wr,
                                             float* y, float* r){
    int node = (blockIdx.x * 256 + threadIdx.x) >> 6;
    int lane = threadIdx.x & 63;
    if (node >= GN) return;
    u32 hv  = ((const u32*)h)[node * 64 + lane];
    u32 wlv = ((const u32*)wl)[lane];
    u32 wrv = ((const u32*)wr)[lane];
    float hlo = bl(hv), hhi = bh(hv);
    float ya = hlo * bl(wlv) + hhi * bh(wlv);
    float ra = hlo * bl(wrv) + hhi * bh(wrv);
    #pragma unroll
    for (int m = 1; m < 64; m <<= 1){ ya += __shfl_xor(ya, m); ra += __shfl_xor(ra, m); }
    if (lane == 0){ y[node] = ya; r[node] = ra; }
}

__global__ void __launch_bounds__(256) k_out(const float* y, const float* r, const int* rowptr,
                                             const int* col, const float* invdeg, const u16* bout,
                                             const int* flags, void* out){
    int n = blockIdx.x * 256 + threadIdx.x;
    if (n >= GN) return;
    int beg = rowptr[n], end = rowptr[n + 1];
    float s = 0.f;
    for (int e = beg; e < end; ++e) s += y[col[e]];
    float z = invdeg[n] * s + r[n] + __uint_as_float(((u32)bout[0]) << 16);
    float sg = 1.f / (1.f + __expf(-z));
    if (flags[1]) ((float*)out)[n] = sg;
    else          ((u16*)out)[n] = f2bf(sg);
}

extern "C" void kernel_launch(void* const* d_in, const int* in_sizes, int n_in,
                              void* d_out, int out_size, void* d_ws, size_t ws_size,
                              hipStream_t stream) {
    const void* x     = d_in[0];
    const int*  ei    = (const int*)d_in[1];
    const void* Wl    = d_in[2];
    const void* Wr    = d_in[3];
    const void* bias  = d_in[4];
    const void* gamma = d_in[5];
    const void* beta  = d_in[6];
    const void* wlout = d_in[7];
    const void* wrout = d_in[8];
    const void* bout  = d_in[9];

    char* p = (char*)d_ws;
    auto take = [&](size_t b){ void* q = (void*)p; p += (b + 255) & ~(size_t)255; return q; };
    int*   deg    = (int*)  take((size_t)GN * 4);
    int*   rowptr = (int*)  take((size_t)(GN + 1) * 4);
    int*   cursor = (int*)  take((size_t)GN * 4);
    int*   bsum   = (int*)  take(512);
    int*   boff   = (int*)  take(512);
    int*   flags  = (int*)  take(256);
    float* invdeg = (float*)take((size_t)GN * 4);
    float* colsum = (float*)take(256 * 4);
    float* scsh   = (float*)take(256 * 4);
    float* yv     = (float*)take((size_t)GN * 4);
    float* rv     = (float*)take((size_t)GN * 4);
    int*   col    = (int*)  take((size_t)GE * 4);
    u16*   xb     = (u16*)  take((size_t)GN * 128 * 2);
    u16*   amean  = (u16*)  take((size_t)GN * 128 * 2);
    u16*   hbuf   = (u16*)  take((size_t)GN * 128 * 2);
    u16*   wbuf   = (u16*)  take((size_t)WTOT * 2);

    const int NB_N = (GN + 255) / 256;          // 391
    const int NB_E = (GE + 255) / 256;          // 6250
    const int NB_S = (GN + 1023) / 1024;        // 98
    const int NB_W = (GN + 3) / 4;              // 25000 (wave per node)
    const int NB_G = (GN + 127) / 128;          // 782
    const int NB_M = (GN * 16 + 255) / 256;     // 6250
    const int NB_C = (WTOT + 255) / 256;        // 390

    k_init <<<NB_N, 256, 0, stream>>>(ei, (const u32*)x, deg, colsum, flags);
    k_convx<<<NB_M, 256, 0, stream>>>(x, flags, xb);
    k_convw<<<NB_C, 256, 0, stream>>>(Wl, Wr, bias, gamma, beta, wlout, wrout, bout, flags, wbuf);
    k_count<<<NB_E, 256, 0, stream>>>(ei, flags, deg);
    k_scan1<<<NB_S, 256, 0, stream>>>(deg, rowptr, bsum);
    k_scan2<<<1,    128, 0, stream>>>(bsum, boff, rowptr);
    k_scan3<<<NB_N, 256, 0, stream>>>(rowptr, cursor, deg, boff, invdeg);
    k_fill <<<NB_E, 256, 0, stream>>>(ei, flags, cursor, col);

    const u16* hin = xb;
    for (int i = 0; i < 3; ++i){
        k_agg <<<NB_W, 256, 0, stream>>>(hin, rowptr, col, invdeg, amean);
        k_gemm<<<NB_G, 256, 0, stream>>>(amean, hin, wbuf + i * 16384, wbuf + WOFF_WR + i * 16384,
                                         wbuf + WOFF_B + i * 128, hbuf, colsum);
        k_bn  <<<1,    256, 0, stream>>>(colsum, wbuf + WOFF_G + i * 128, wbuf + WOFF_BE + i * 128, scsh);
        k_norm<<<NB_M, 256, 0, stream>>>(hbuf, scsh);
        hin = hbuf;
    }
    k_dot<<<NB_W, 256, 0, stream>>>(hbuf, wbuf + WOFF_WLO, wbuf + WOFF_WRO, yv, rv);
    k_out<<<NB_N, 256, 0, stream>>>(yv, rv, rowptr, col, invdeg, wbuf + WOFF_BO, flags, d_out);
}